// Round 2
// baseline (871.771 us; speedup 1.0000x reference)
//
#include <hip/hip_runtime.h>
#include <math.h>

#define NROWS 6144
#define LSIG  5000
#define NT    256

// db4 decomposition filters (natural order), hi[k] = (-1)^(k+1) lo[k]
#define DL0 (-0.010597401784997278f)
#define DL1 ( 0.032883011666982945f)
#define DL2 ( 0.030841381835986965f)
#define DL3 (-0.18703481171888114f)
#define DL4 (-0.02798376941698385f)
#define DL5 ( 0.6308807679295904f)
#define DL6 ( 0.7148465705525415f)
#define DL7 ( 0.23037781330885523f)
#define DH0 ( 0.010597401784997278f)
#define DH1 ( 0.032883011666982945f)
#define DH2 (-0.030841381835986965f)
#define DH3 (-0.18703481171888114f)
#define DH4 ( 0.02798376941698385f)
#define DH5 ( 0.6308807679295904f)
#define DH6 (-0.7148465705525415f)
#define DH7 ( 0.23037781330885523f)

// Forward DWT sample: ca[k] = sum_t xp[2k+t]*lo[7-t], hp likewise.
// xp index map (reflect pad 7,7 then drop first): j'=2k+t-6; i=|j'|; if i>=L -> 2L-2-i
__device__ __forceinline__ void dwt_pair(const float* __restrict__ src, int L, int k,
                                         float& a, float& b) {
    const float LO[8] = {DL0,DL1,DL2,DL3,DL4,DL5,DL6,DL7};
    const float HI[8] = {DH0,DH1,DH2,DH3,DH4,DH5,DH6,DH7};
    a = 0.f; b = 0.f;
    int base = 2*k - 6;
#pragma unroll
    for (int t = 0; t < 8; ++t) {
        int j = base + t;
        int i = (j < 0) ? -j : j;
        if (i >= L) i = 2*L - 2 - i;
        float v = src[i];
        a += v * LO[7-t];
        b += v * HI[7-t];
    }
}

// Inverse lowpass-only: out[o] = sum_m ca[m]*dec_lo[1+2m-o], m in [floor(o/2), floor((o+6)/2)] clamped to C
__device__ __forceinline__ float idwt_lo_at(const float* __restrict__ ca, int C, int o) {
    int m0 = o >> 1;
    float s = 0.f;
    if (o & 1) {
        if (m0     < C) s += ca[m0    ] * DL0;
        if (m0 + 1 < C) s += ca[m0 + 1] * DL2;
        if (m0 + 2 < C) s += ca[m0 + 2] * DL4;
        if (m0 + 3 < C) s += ca[m0 + 3] * DL6;
    } else {
        if (m0     < C) s += ca[m0    ] * DL1;
        if (m0 + 1 < C) s += ca[m0 + 1] * DL3;
        if (m0 + 2 < C) s += ca[m0 + 2] * DL5;
        if (m0 + 3 < C) s += ca[m0 + 3] * DL7;
    }
    return s;
}

// Full inverse: ca + cd channels
__device__ __forceinline__ float idwt_at(const float* __restrict__ ca, const float* __restrict__ cd,
                                         int C, int o) {
    int m0 = o >> 1;
    float s = 0.f;
    if (o & 1) {
        if (m0     < C) s += ca[m0    ] * DL0 + cd[m0    ] * DH0;
        if (m0 + 1 < C) s += ca[m0 + 1] * DL2 + cd[m0 + 1] * DH2;
        if (m0 + 2 < C) s += ca[m0 + 2] * DL4 + cd[m0 + 2] * DH4;
        if (m0 + 3 < C) s += ca[m0 + 3] * DL6 + cd[m0 + 3] * DH6;
    } else {
        if (m0     < C) s += ca[m0    ] * DL1 + cd[m0    ] * DH1;
        if (m0 + 1 < C) s += ca[m0 + 1] * DL3 + cd[m0 + 1] * DH3;
        if (m0 + 2 < C) s += ca[m0 + 2] * DL5 + cd[m0 + 2] * DH5;
        if (m0 + 3 < C) s += ca[m0 + 3] * DL7 + cd[m0 + 3] * DH7;
    }
    return s;
}

// ---------------- Kernel A: baseline removal + forward 4-level DWT ----------------
// NOTE: no const arrays of __shared__ pointers (gfx950 backend rejects the
// addrspacecast static initializer) — use integer offsets into one LDS arena.
__global__ __launch_bounds__(NT) void kernelA(const float* __restrict__ x,
                                              float* __restrict__ g_d1, float* __restrict__ g_d2,
                                              float* __restrict__ g_d3, float* __restrict__ g_d4,
                                              float* __restrict__ g_ca4) {
    __shared__ float sig0[5000];
    __shared__ float pyr[5044];    // levels 1..9: 2503,1255,631,319,163,85,46,26,16
    __shared__ float recA[1255];   // even-k recon buffer
    __shared__ float recB[2503];   // odd-k recon buffer
    __shared__ float ssds[9];
    __shared__ float red[4];
    __shared__ int depth_s;

    const int row = blockIdx.x;
    const int tid = threadIdx.x;

    // load row (vectorized: 5000 = 1250*4, 20000B row stride is 16B aligned)
    {
        const float4* xr4 = (const float4*)(x + (size_t)row * LSIG);
        float4* s4 = (float4*)sig0;
        for (int i = tid; i < 1250; i += NT) s4[i] = xr4[i];
    }
    __syncthreads();

    const int lensA[10] = {5000, 2503, 1255, 631, 319, 163, 85, 46, 26, 16};
    const int offs[9]   = {0, 2503, 3758, 4389, 4708, 4871, 4956, 5002, 5028};

    // ---- phase 1: pyramid with hp-SSD per level ----
    const float* src = sig0;
#pragma unroll
    for (int t = 0; t < 9; ++t) {
        const int L  = lensA[t];
        const int Lo = lensA[t + 1];
        float* lp = pyr + offs[t];
        float part = 0.f;
        for (int k = tid; k < Lo; k += NT) {
            float a, b;
            dwt_pair(src, L, k, a, b);
            lp[k] = a;
            part += b * b;
        }
#pragma unroll
        for (int o = 32; o; o >>= 1) part += __shfl_down(part, o, 64);
        if ((tid & 63) == 0) red[tid >> 6] = part;
        __syncthreads();
        if (tid == 0) ssds[t] = red[0] + red[1] + red[2] + red[3];
        __syncthreads();
        src = lp;
    }

    // ---- depth decision ----
    if (tid == 0) {
        int dd = -1;
        for (int t = 2; t <= 8; ++t)
            if (dd < 0 && ssds[t - 2] > ssds[t - 1] && ssds[t - 1] < ssds[t]) dd = t;
        depth_s = (dd < 0) ? 8 : dd;
    }
    __syncthreads();
    const int d = depth_s;   // in [2,8] -> sigs[d] = pyr + offs[d-1]

    // ---- baseline reconstruction: bl = (idwt_lo)^d (sigs[d]); subtract into sig0 ----
    const float* cur = pyr + offs[d - 1];
    int Lc = lensA[d];
    for (int k = d - 1; k >= 1; --k) {
        int ol = lensA[k];
        float* dst = (k & 1) ? recB : recA;
        for (int o = tid; o < ol; o += NT) dst[o] = idwt_lo_at(cur, Lc, o);
        __syncthreads();
        cur = dst; Lc = ol;
    }
    for (int o = tid; o < 5000; o += NT) sig0[o] -= idwt_lo_at(cur, Lc, o);
    __syncthreads();

    // ---- phase 2: 4-level forward DWT of residual; details -> global ----
    const int l2[5] = {5000, 2503, 1255, 631, 319};
    src = sig0;
#pragma unroll
    for (int lev = 0; lev < 4; ++lev) {
        const int L  = l2[lev];
        const int Lo = l2[lev + 1];
        float* lp = (lev & 1) ? recA : recB;   // 0:recB 1:recA 2:recB 3:recA
        float* hg;
        if      (lev == 0) hg = g_d1 + (size_t)row * 2503;
        else if (lev == 1) hg = g_d2 + (size_t)row * 1255;
        else if (lev == 2) hg = g_d3 + (size_t)row * 631;
        else               hg = g_d4 + (size_t)row * 319;
        for (int k = tid; k < Lo; k += NT) {
            float a, b;
            dwt_pair(src, L, k, a, b);
            lp[k] = a;
            hg[k] = b;
        }
        __syncthreads();
        src = lp;
    }
    float* cg = g_ca4 + (size_t)row * 319;
    for (int i = tid; i < 319; i += NT) cg[i] = recA[i];
}

// ---------------- median radix-select kernels ----------------
__global__ void kinit(unsigned* bins, unsigned* state) {
    int i = blockIdx.x * blockDim.x + threadIdx.x;
    if (i < 2048) bins[i] = 0u;
    if (i == 0) { state[0] = 0u; state[1] = 979967u; }  // k = (1959936-1)//2
}

__global__ void khist(const float* __restrict__ data, int n, unsigned* __restrict__ bins,
                      const unsigned* __restrict__ state, int shift, unsigned binmask,
                      unsigned prefmask) {
    __shared__ unsigned h[2048];
    const int nb = (int)binmask + 1;
    for (int i = threadIdx.x; i < nb; i += blockDim.x) h[i] = 0u;
    __syncthreads();
    const unsigned pref = state[0] & prefmask;
    const int stride = gridDim.x * blockDim.x;
    for (int i = blockIdx.x * blockDim.x + threadIdx.x; i < n; i += stride) {
        unsigned key = __float_as_uint(fabsf(data[i]));
        if ((key & prefmask) == pref) atomicAdd(&h[(key >> shift) & binmask], 1u);
    }
    __syncthreads();
    for (int i = threadIdx.x; i < nb; i += blockDim.x)
        if (h[i]) atomicAdd(&bins[i], h[i]);
}

__global__ void kselect(unsigned* bins, unsigned* state, float* sigma_out,
                        int shift, int nbins, int final_pass) {
    if (threadIdx.x == 0) {
        unsigned krem = state[1];
        unsigned prefix = state[0];
        unsigned cum = 0;
        int b = 0;
        for (; b < nbins - 1; ++b) {
            unsigned c = bins[b];
            if (cum + c > krem) break;
            cum += c;
        }
        prefix |= ((unsigned)b) << shift;
        state[0] = prefix;
        state[1] = krem - cum;
        if (final_pass) *sigma_out = __uint_as_float(prefix) / 0.6745f;
    }
    __syncthreads();
    for (int i = threadIdx.x; i < nbins; i += blockDim.x) bins[i] = 0u;
}

// ---------------- Kernel C: threshold + inverse DWT + normalize ----------------
__global__ __launch_bounds__(NT) void kernelC(const float* __restrict__ g_d1,
                                              const float* __restrict__ g_d2,
                                              const float* __restrict__ g_d3,
                                              const float* __restrict__ g_d4,
                                              const float* __restrict__ g_ca4,
                                              const float* __restrict__ sigma_p,
                                              float* __restrict__ out) {
    __shared__ float A[5000];
    __shared__ float B[2504];
    __shared__ float Dd[2503];
    __shared__ double redd[4];
    __shared__ float sg;

    const int row = blockIdx.x;
    const int tid = threadIdx.x;
    if (tid == 0) sg = *sigma_p;
    for (int i = tid; i < 319; i += NT) A[i] = g_ca4[(size_t)row * 319 + i];
    __syncthreads();
    const float sigma = sg;

    const int Cs[4] = {319, 631, 1255, 2503};
    const int Os[4] = {632, 1256, 2504, 5000};

#pragma unroll
    for (int s = 0; s < 4; ++s) {
        const int C = Cs[s];
        const int O = Os[s];
        const float* dg;
        if      (s == 0) dg = g_d4 + (size_t)row * 319;
        else if (s == 1) dg = g_d3 + (size_t)row * 631;
        else if (s == 2) dg = g_d2 + (size_t)row * 1255;
        else             dg = g_d1 + (size_t)row * 2503;
        const float* sp = (s & 1) ? B : A;   // 0:A 1:B 2:A 3:B
        float* dp       = (s & 1) ? A : B;
        for (int i = tid; i < C; i += NT) {
            float v = dg[i];
            Dd[i] = (v < sigma) ? 0.f : v;   // raw-value threshold, per reference
        }
        __syncthreads();
        for (int o = tid; o < O; o += NT) dp[o] = idwt_at(sp, Dd, C, o);
        __syncthreads();
    }

    // normalize A[0..4999]: mean, std(ddof=1), nan_to_num
    double part = 0.0;
    for (int i = tid; i < 5000; i += NT) part += (double)A[i];
#pragma unroll
    for (int o = 32; o; o >>= 1) part += __shfl_down(part, o, 64);
    if ((tid & 63) == 0) redd[tid >> 6] = part;
    __syncthreads();
    double mean = (redd[0] + redd[1] + redd[2] + redd[3]) / 5000.0;
    __syncthreads();

    double p2 = 0.0;
    for (int i = tid; i < 5000; i += NT) {
        double df = (double)A[i] - mean;
        p2 += df * df;
    }
#pragma unroll
    for (int o = 32; o; o >>= 1) p2 += __shfl_down(p2, o, 64);
    if ((tid & 63) == 0) redd[tid >> 6] = p2;
    __syncthreads();
    double var = (redd[0] + redd[1] + redd[2] + redd[3]) / 4999.0;

    float meanf = (float)mean;
    float stdf = (float)sqrt(var);
    float inv = 1.0f / stdf;
    float* orow = out + (size_t)row * 5000;
    for (int i = tid; i < 5000; i += NT) {
        float r = (A[i] - meanf) * inv;
        if (isnan(r)) r = 0.f;
        else if (isinf(r)) r = copysignf(3.4028234663852886e38f, r);
        orow[i] = r;
    }
}

extern "C" void kernel_launch(void* const* d_in, const int* in_sizes, int n_in,
                              void* d_out, int out_size, void* d_ws, size_t ws_size,
                              hipStream_t stream) {
    const float* x = (const float*)d_in[0];
    float* out = (float*)d_out;

    const size_t n1 = (size_t)NROWS * 2503;
    const size_t n2 = (size_t)NROWS * 1255;
    const size_t n3 = (size_t)NROWS * 631;
    const size_t n4 = (size_t)NROWS * 319;

    float* w    = (float*)d_ws;
    float* d1   = w;
    float* d2   = d1 + n1;
    float* d3   = d2 + n2;
    float* d4   = d3 + n3;
    float* ca4  = d4 + n4;
    unsigned* bins  = (unsigned*)(ca4 + n4);
    unsigned* state = bins + 2048;
    float* sigp = (float*)(state + 2);
    const int n = (int)n4;  // 1,959,936

    hipLaunchKernelGGL(kernelA, dim3(NROWS), dim3(NT), 0, stream, x, d1, d2, d3, d4, ca4);
    hipLaunchKernelGGL(kinit, dim3(8), dim3(256), 0, stream, bins, state);
    hipLaunchKernelGGL(khist, dim3(512), dim3(256), 0, stream, d4, n, bins, state, 21, 2047u, 0x00000000u);
    hipLaunchKernelGGL(kselect, dim3(1), dim3(256), 0, stream, bins, state, sigp, 21, 2048, 0);
    hipLaunchKernelGGL(khist, dim3(512), dim3(256), 0, stream, d4, n, bins, state, 10, 2047u, 0xFFE00000u);
    hipLaunchKernelGGL(kselect, dim3(1), dim3(256), 0, stream, bins, state, sigp, 10, 2048, 0);
    hipLaunchKernelGGL(khist, dim3(512), dim3(256), 0, stream, d4, n, bins, state, 0, 1023u, 0xFFFFFC00u);
    hipLaunchKernelGGL(kselect, dim3(1), dim3(256), 0, stream, bins, state, sigp, 0, 1024, 1);
    hipLaunchKernelGGL(kernelC, dim3(NROWS), dim3(NT), 0, stream, d1, d2, d3, d4, ca4, sigp, out);
}

// Round 3
// 497.104 us; speedup vs baseline: 1.7537x; 1.7537x over previous
//
#include <hip/hip_runtime.h>
#include <math.h>

#define NROWS 6144
#define LSIG  5000
#define NT    256

// db4 decomposition filters (natural order), hi[k] = (-1)^(k+1) lo[k]
#define DL0 (-0.010597401784997278f)
#define DL1 ( 0.032883011666982945f)
#define DL2 ( 0.030841381835986965f)
#define DL3 (-0.18703481171888114f)
#define DL4 (-0.02798376941698385f)
#define DL5 ( 0.6308807679295904f)
#define DL6 ( 0.7148465705525415f)
#define DL7 ( 0.23037781330885523f)
#define DH0 ( 0.010597401784997278f)
#define DH1 ( 0.032883011666982945f)
#define DH2 (-0.030841381835986965f)
#define DH3 (-0.18703481171888114f)
#define DH4 ( 0.02798376941698385f)
#define DH5 ( 0.6308807679295904f)
#define DH6 (-0.7148465705525415f)
#define DH7 ( 0.23037781330885523f)

// Forward DWT (edge path): ca[k] = sum_t xp[2k+t]*lo[7-t].
// xp index map (reflect pad 7,7 drop first): j=2k+t-6; i=|j|; if i>=L -> 2L-2-i
__device__ __forceinline__ void dwt_pair_edge(const float* __restrict__ src, int L, int k,
                                              float& a, float& b) {
    const float LO[8] = {DL0,DL1,DL2,DL3,DL4,DL5,DL6,DL7};
    const float HI[8] = {DH0,DH1,DH2,DH3,DH4,DH5,DH6,DH7};
    a = 0.f; b = 0.f;
    int base = 2*k - 6;
#pragma unroll
    for (int t = 0; t < 8; ++t) {
        int j = base + t;
        int i = (j < 0) ? -j : j;
        if (i >= L) i = 2*L - 2 - i;
        float v = src[i];
        a += v * LO[7-t];
        b += v * HI[7-t];
    }
}

// Interior fast path: valid when base >= 0 and base+7 <= L-1  (k>=3 && 2k+1<L)
__device__ __forceinline__ void dwt_pair_int(const float* __restrict__ src, int k,
                                             float& a, float& b) {
    int base = 2*k - 6;
    float v0 = src[base],     v1 = src[base + 1], v2 = src[base + 2], v3 = src[base + 3];
    float v4 = src[base + 4], v5 = src[base + 5], v6 = src[base + 6], v7 = src[base + 7];
    a = v0*DL7 + v1*DL6 + v2*DL5 + v3*DL4 + v4*DL3 + v5*DL2 + v6*DL1 + v7*DL0;
    b = v0*DH7 + v1*DH6 + v2*DH5 + v3*DH4 + v4*DH3 + v5*DH2 + v6*DH1 + v7*DH0;
}

// Pair-form lowpass-only inverse: outputs o=2m (even) and o=2m+1 (odd) share ca[m..m+3].
// No bounds checks needed: for all our (O,C), (O-1)/2 + 3 < C holds.
__device__ __forceinline__ void idwt_lo_pair(const float* __restrict__ ca, int m,
                                             float& ev, float& od) {
    float c0 = ca[m], c1 = ca[m+1], c2 = ca[m+2], c3 = ca[m+3];
    ev = c0*DL1 + c1*DL3 + c2*DL5 + c3*DL7;
    od = c0*DL0 + c1*DL2 + c2*DL4 + c3*DL6;
}

__device__ __forceinline__ void idwt_pair(const float* __restrict__ ca, const float* __restrict__ cd,
                                          int m, float& ev, float& od) {
    float c0 = ca[m], c1 = ca[m+1], c2 = ca[m+2], c3 = ca[m+3];
    float e0 = cd[m], e1 = cd[m+1], e2 = cd[m+2], e3 = cd[m+3];
    ev = c0*DL1 + c1*DL3 + c2*DL5 + c3*DL7 + e0*DH1 + e1*DH3 + e2*DH5 + e3*DH7;
    od = c0*DL0 + c1*DL2 + c2*DL4 + c3*DL6 + e0*DH0 + e1*DH2 + e2*DH4 + e3*DH6;
}

// ---------------- Kernel A: baseline removal + forward 4-level DWT ----------------
// LDS 40.3 KB -> 4 blocks/CU. Recon ping-pong overlaid into dead pyr prefix:
// slot0 @pyr+0 (<=2503), slot1 @pyr+2503 (<=1255); sigs[k<d] are dead post-depth.
__global__ __launch_bounds__(NT, 4) void kernelA(const float* __restrict__ x,
                                                 float* __restrict__ g_d1, float* __restrict__ g_d2,
                                                 float* __restrict__ g_d3, float* __restrict__ g_d4,
                                                 float* __restrict__ g_ca4) {
    __shared__ float sig0[5000];
    __shared__ float pyr[5028];    // levels 1..8: 2503,1255,631,319,163,85,46,26
    __shared__ float redm[9][4];
    __shared__ int depth_s;

    const int row = blockIdx.x;
    const int tid = threadIdx.x;

    {
        const float4* xr4 = (const float4*)(x + (size_t)row * LSIG);
        float4* s4 = (float4*)sig0;
        for (int i = tid; i < 1250; i += NT) s4[i] = xr4[i];
    }
    __syncthreads();

    const int lensA[10] = {5000, 2503, 1255, 631, 319, 163, 85, 46, 26, 16};
    const int offs[8]   = {0, 2503, 3758, 4389, 4708, 4871, 4956, 5002};

    // ---- phase 1: pyramid; per-thread SSD accumulators (t=8 lowpass is discarded) ----
    float sp[9];
    const float* src = sig0;
#pragma unroll
    for (int t = 0; t < 9; ++t) {
        const int L   = lensA[t];
        const int Lo  = lensA[t + 1];
        const int kHi = (L - 2) >> 1;           // max k with 2k+1 <= L-1
        float* lp = pyr + ((t < 8) ? offs[t] : 0);
        float part = 0.f;
        for (int k = tid; k < Lo; k += NT) {
            float a, b;
            if (k >= 3 && k <= kHi) dwt_pair_int(src, k, a, b);
            else                    dwt_pair_edge(src, L, k, a, b);
            if (t < 8) lp[k] = a;
            part += b * b;
        }
        sp[t] = part;
        __syncthreads();
        src = lp;
    }

    // ---- one reduction for all 9 SSDs, then depth decision ----
#pragma unroll
    for (int t = 0; t < 9; ++t) {
        float p = sp[t];
#pragma unroll
        for (int o = 32; o; o >>= 1) p += __shfl_down(p, o, 64);
        if ((tid & 63) == 0) redm[t][tid >> 6] = p;
    }
    __syncthreads();
    if (tid == 0) {
        float ssds[9];
#pragma unroll
        for (int t = 0; t < 9; ++t) ssds[t] = redm[t][0] + redm[t][1] + redm[t][2] + redm[t][3];
        int dd = -1;
        for (int t = 2; t <= 8; ++t)
            if (dd < 0 && ssds[t - 2] > ssds[t - 1] && ssds[t - 1] < ssds[t]) dd = t;
        depth_s = (dd < 0) ? 8 : dd;
    }
    __syncthreads();
    const int d = depth_s;   // in [2,8]; sigs[d] = pyr + offs[d-1]

    // ---- baseline recon: (idwt_lo)^d of sigs[d], ping-pong in dead prefix; subtract ----
    const float* cur = pyr + offs[d - 1];
    for (int k = d - 1; k >= 1; --k) {
        const int ol = lensA[k];
        float* dst = (k & 1) ? pyr : (pyr + 2503);   // slot0 / slot1
        const int np = (ol + 1) >> 1;
        for (int m = tid; m < np; m += NT) {
            float ev, od;
            idwt_lo_pair(cur, m, ev, od);
            dst[2*m] = ev;
            if (2*m + 1 < ol) dst[2*m + 1] = od;
        }
        __syncthreads();
        cur = dst;
    }
    for (int m = tid; m < 2500; m += NT) {
        float ev, od;
        idwt_lo_pair(cur, m, ev, od);    // cur = slot0, len 2503
        sig0[2*m]     -= ev;
        sig0[2*m + 1] -= od;
    }
    __syncthreads();

    // ---- phase 2: 4-level forward DWT of residual; details -> global, lp in pyr ----
    const int l2[5] = {5000, 2503, 1255, 631, 319};
    src = sig0;
#pragma unroll
    for (int lev = 0; lev < 4; ++lev) {
        const int L   = l2[lev];
        const int Lo  = l2[lev + 1];
        const int kHi = (L - 2) >> 1;
        float* lp = pyr + ((lev & 1) ? 2503 : 0);
        float* hg;
        if      (lev == 0) hg = g_d1 + (size_t)row * 2503;
        else if (lev == 1) hg = g_d2 + (size_t)row * 1255;
        else if (lev == 2) hg = g_d3 + (size_t)row * 631;
        else               hg = g_d4 + (size_t)row * 319;
        for (int k = tid; k < Lo; k += NT) {
            float a, b;
            if (k >= 3 && k <= kHi) dwt_pair_int(src, k, a, b);
            else                    dwt_pair_edge(src, L, k, a, b);
            lp[k] = a;
            hg[k] = b;
        }
        __syncthreads();
        src = lp;
    }
    float* cg = g_ca4 + (size_t)row * 319;
    for (int i = tid; i < 319; i += NT) cg[i] = pyr[2503 + i];
}

// ---------------- median radix-select kernels ----------------
__global__ void kinit(unsigned* bins, unsigned* state) {
    int i = blockIdx.x * blockDim.x + threadIdx.x;
    if (i < 2048) bins[i] = 0u;
    if (i == 0) { state[0] = 0u; state[1] = 979967u; }  // k = (1959936-1)//2
}

__global__ void khist(const float* __restrict__ data, int n, unsigned* __restrict__ bins,
                      const unsigned* __restrict__ state, int shift, unsigned binmask,
                      unsigned prefmask) {
    __shared__ unsigned h[2048];
    const int nb = (int)binmask + 1;
    for (int i = threadIdx.x; i < nb; i += blockDim.x) h[i] = 0u;
    __syncthreads();
    const unsigned pref = state[0] & prefmask;
    const int stride = gridDim.x * blockDim.x;
    for (int i = blockIdx.x * blockDim.x + threadIdx.x; i < n; i += stride) {
        unsigned key = __float_as_uint(fabsf(data[i]));
        if ((key & prefmask) == pref) atomicAdd(&h[(key >> shift) & binmask], 1u);
    }
    __syncthreads();
    for (int i = threadIdx.x; i < nb; i += blockDim.x)
        if (h[i]) atomicAdd(&bins[i], h[i]);
}

__global__ void kselect(unsigned* bins, unsigned* state, float* sigma_out,
                        int shift, int nbins, int final_pass) {
    if (threadIdx.x == 0) {
        unsigned krem = state[1];
        unsigned prefix = state[0];
        unsigned cum = 0;
        int b = 0;
        for (; b < nbins - 1; ++b) {
            unsigned c = bins[b];
            if (cum + c > krem) break;
            cum += c;
        }
        prefix |= ((unsigned)b) << shift;
        state[0] = prefix;
        state[1] = krem - cum;
        if (final_pass) *sigma_out = __uint_as_float(prefix) / 0.6745f;
    }
    __syncthreads();
    for (int i = threadIdx.x; i < nbins; i += blockDim.x) bins[i] = 0u;
}

// ---------------- Kernel C: threshold + inverse DWT + normalize ----------------
__global__ __launch_bounds__(NT, 4) void kernelC(const float* __restrict__ g_d1,
                                                 const float* __restrict__ g_d2,
                                                 const float* __restrict__ g_d3,
                                                 const float* __restrict__ g_d4,
                                                 const float* __restrict__ g_ca4,
                                                 const float* __restrict__ sigma_p,
                                                 float* __restrict__ out) {
    __shared__ float A[5000];
    __shared__ float B[2504];
    __shared__ float Dd[2503];
    __shared__ double redd[4][2];
    __shared__ float sg;

    const int row = blockIdx.x;
    const int tid = threadIdx.x;
    if (tid == 0) sg = *sigma_p;
    for (int i = tid; i < 319; i += NT) A[i] = g_ca4[(size_t)row * 319 + i];
    __syncthreads();
    const float sigma = sg;

    const int Cs[4] = {319, 631, 1255, 2503};
    const int Os[4] = {632, 1256, 2504, 5000};

#pragma unroll
    for (int s = 0; s < 4; ++s) {
        const int C = Cs[s];
        const int O = Os[s];
        const float* dg;
        if      (s == 0) dg = g_d4 + (size_t)row * 319;
        else if (s == 1) dg = g_d3 + (size_t)row * 631;
        else if (s == 2) dg = g_d2 + (size_t)row * 1255;
        else             dg = g_d1 + (size_t)row * 2503;
        const float* spb = (s & 1) ? B : A;   // 0:A 1:B 2:A 3:B
        float* dp        = (s & 1) ? A : B;
        for (int i = tid; i < C; i += NT) {
            float v = dg[i];
            Dd[i] = (v < sigma) ? 0.f : v;   // raw-value threshold, per reference
        }
        __syncthreads();
        const int np = O >> 1;               // O always even
        for (int m = tid; m < np; m += NT) {
            float ev, od;
            idwt_pair(spb, Dd, m, ev, od);
            dp[2*m]     = ev;
            dp[2*m + 1] = od;
        }
        __syncthreads();
    }

    // normalize A[0..4999]: single-pass sum/sumsq in double, std(ddof=1), nan_to_num
    double s1 = 0.0, s2 = 0.0;
    for (int i = tid; i < 5000; i += NT) {
        double v = (double)A[i];
        s1 += v;
        s2 += v * v;
    }
#pragma unroll
    for (int o = 32; o; o >>= 1) {
        s1 += __shfl_down(s1, o, 64);
        s2 += __shfl_down(s2, o, 64);
    }
    if ((tid & 63) == 0) { redd[tid >> 6][0] = s1; redd[tid >> 6][1] = s2; }
    __syncthreads();
    double sum  = redd[0][0] + redd[1][0] + redd[2][0] + redd[3][0];
    double sumq = redd[0][1] + redd[1][1] + redd[2][1] + redd[3][1];
    double mean = sum / 5000.0;
    double var  = (sumq - sum * mean) / 4999.0;

    float meanf = (float)mean;
    float inv = 1.0f / (float)sqrt(var);
    float* orow = out + (size_t)row * 5000;
    for (int i = tid; i < 5000; i += NT) {
        float r = (A[i] - meanf) * inv;
        if (isnan(r)) r = 0.f;
        else if (isinf(r)) r = copysignf(3.4028234663852886e38f, r);
        orow[i] = r;
    }
}

extern "C" void kernel_launch(void* const* d_in, const int* in_sizes, int n_in,
                              void* d_out, int out_size, void* d_ws, size_t ws_size,
                              hipStream_t stream) {
    const float* x = (const float*)d_in[0];
    float* out = (float*)d_out;

    const size_t n1 = (size_t)NROWS * 2503;
    const size_t n2 = (size_t)NROWS * 1255;
    const size_t n3 = (size_t)NROWS * 631;
    const size_t n4 = (size_t)NROWS * 319;

    float* w    = (float*)d_ws;
    float* d1   = w;
    float* d2   = d1 + n1;
    float* d3   = d2 + n2;
    float* d4   = d3 + n3;
    float* ca4  = d4 + n4;
    unsigned* bins  = (unsigned*)(ca4 + n4);
    unsigned* state = bins + 2048;
    float* sigp = (float*)(state + 2);
    const int n = (int)n4;  // 1,959,936

    hipLaunchKernelGGL(kernelA, dim3(NROWS), dim3(NT), 0, stream, x, d1, d2, d3, d4, ca4);
    hipLaunchKernelGGL(kinit, dim3(8), dim3(256), 0, stream, bins, state);
    hipLaunchKernelGGL(khist, dim3(512), dim3(256), 0, stream, d4, n, bins, state, 21, 2047u, 0x00000000u);
    hipLaunchKernelGGL(kselect, dim3(1), dim3(256), 0, stream, bins, state, sigp, 21, 2048, 0);
    hipLaunchKernelGGL(khist, dim3(512), dim3(256), 0, stream, d4, n, bins, state, 10, 2047u, 0xFFE00000u);
    hipLaunchKernelGGL(kselect, dim3(1), dim3(256), 0, stream, bins, state, sigp, 10, 2048, 0);
    hipLaunchKernelGGL(khist, dim3(512), dim3(256), 0, stream, d4, n, bins, state, 0, 1023u, 0xFFFFFC00u);
    hipLaunchKernelGGL(kselect, dim3(1), dim3(256), 0, stream, bins, state, sigp, 0, 1024, 1);
    hipLaunchKernelGGL(kernelC, dim3(NROWS), dim3(NT), 0, stream, d1, d2, d3, d4, ca4, sigp, out);
}